// Round 8
// baseline (424.811 us; speedup 1.0000x reference)
//
#include <hip/hip_runtime.h>
#include <math.h>

#define N_NODES 100000
#define N_EDGES 1600000
#define LN_EPS 1e-5f
#define NORM_EPS 1e-12f
#define SCAN_TILE 1024
#define N_TILES ((N_NODES + SCAN_TILE - 1) / SCAN_TILE)   // 98
#define ROWS_PER_BLOCK 32
#define GEMM_BLOCKS (N_NODES / ROWS_PER_BLOCK)            // 3125, exact
#define WSTRIDE 66   // dword stride: even (b64-aligned) and 2c+k -> 2-way banks (free)

// bf16 helpers (round-to-nearest-even)
__device__ __forceinline__ unsigned short f2bf(float f) {
    unsigned int u = __float_as_uint(f);
    u += 0x7FFFu + ((u >> 16) & 1u);
    return (unsigned short)(u >> 16);
}
__device__ __forceinline__ float bf2f(unsigned short h) {
    return __uint_as_float(((unsigned int)h) << 16);
}

// ---------------------------------------------------------------------------
// K1: h = x @ W^T + b (N x 64) -> bf16; per-node attn scores; fused edge
// count (2 edges/thread, atomics AFTER the k-loop).
// K-LOOP DELIBERATELY NOT UNROLLED (#pragma unroll 1): R5/R6 measured the
// unrolled version spilling acc[] at ANY VGPR budget (2.0/0.95 GB scratch
// writes).  Rolled loop keeps live set ~30 VGPRs.  No min-waves hint.
// ---------------------------------------------------------------------------
__global__ __launch_bounds__(256) void k_gemm(
    const float* __restrict__ x, const float* __restrict__ W,
    const float* __restrict__ b, const float* __restrict__ a,
    const int* __restrict__ ei, int* __restrict__ counts,
    unsigned short* __restrict__ h16,
    float* __restrict__ s_src, float* __restrict__ s_dst)
{
    __shared__ float WL[64 * WSTRIDE];            // WL[c*66 + k] = W[c][k]
    __shared__ float xs[ROWS_PER_BLOCK * 64];
    const int tid  = threadIdx.x;
    const int lane = tid & 63;
    const int wv   = tid >> 6;

    for (int idx = tid * 4; idx < 64 * 64; idx += 256 * 4) {
        const float4 w = *(const float4*)(W + idx);
        const int c = idx >> 6, k = idx & 63;
        WL[c * WSTRIDE + k + 0] = w.x;
        WL[c * WSTRIDE + k + 1] = w.y;
        WL[c * WSTRIDE + k + 2] = w.z;
        WL[c * WSTRIDE + k + 3] = w.w;
    }
    const int row0 = blockIdx.x * ROWS_PER_BLOCK;
    for (int idx = tid * 4; idx < ROWS_PER_BLOCK * 64; idx += 256 * 4)
        *(float4*)(xs + idx) = *(const float4*)(x + (size_t)row0 * 64 + idx);
    __syncthreads();

    const float bias = b[lane];
    float acc[8];
    #pragma unroll
    for (int r = 0; r < 8; ++r) acc[r] = bias;

    const int rbase = wv * 8;
    const float* wrow = WL + lane * WSTRIDE;
    const float* xrow = xs + rbase * 64;
    #pragma unroll 1   // DO NOT unroll: keeps live set small (see header)
    for (int kk = 0; kk < 64; kk += 4) {
        const float2 w01 = *(const float2*)(wrow + kk);
        const float2 w23 = *(const float2*)(wrow + kk + 2);
        #pragma unroll
        for (int r = 0; r < 8; ++r) {
            const float4 xq = *(const float4*)(xrow + r * 64 + kk);
            acc[r] += xq.x * w01.x + xq.y * w01.y + xq.z * w23.x + xq.w * w23.y;
        }
    }

    // fused out-degree count: no __syncthreads after this point
    {
        const int e0 = blockIdx.x * 256 + tid;
        atomicAdd(&counts[ei[e0]], 1);
        atomicAdd(&counts[ei[e0 + GEMM_BLOCKS * 256]], 1);
    }

    const float asrc = a[(lane >> 3) * 16 + (lane & 7)];
    const float adst = a[(lane >> 3) * 16 + 8 + (lane & 7)];
    #pragma unroll
    for (int r = 0; r < 8; ++r) {
        const int row = row0 + rbase + r;
        const float v = acc[r];
        h16[(size_t)row * 64 + lane] = f2bf(v);
        float p = v * asrc, q = v * adst;
        p += __shfl_xor(p, 1);  q += __shfl_xor(q, 1);
        p += __shfl_xor(p, 2);  q += __shfl_xor(q, 2);
        p += __shfl_xor(p, 4);  q += __shfl_xor(q, 4);
        if ((lane & 7) == 0) {
            s_src[row * 8 + (lane >> 3)] = p;
            s_dst[row * 8 + (lane >> 3)] = q;
        }
    }
}

// ---------------------------------------------------------------------------
// Scan stage 1: per-tile (1024) exclusive scan + tile totals.
// ---------------------------------------------------------------------------
__global__ __launch_bounds__(1024) void k_scan1(
    const int* __restrict__ counts, int* __restrict__ row_ptr,
    int* __restrict__ blksum)
{
    __shared__ int wsum[16];
    const int tid = threadIdx.x, lane = tid & 63, wv = tid >> 6;
    const int i = blockIdx.x * SCAN_TILE + tid;
    int v = (i < N_NODES) ? counts[i] : 0;
    int sc = v;
    #pragma unroll
    for (int off = 1; off < 64; off <<= 1) {
        int t = __shfl_up(sc, off);
        if (lane >= off) sc += t;
    }
    if (lane == 63) wsum[wv] = sc;
    __syncthreads();
    if (tid < 16) {
        int ws = wsum[tid];
        #pragma unroll
        for (int off = 1; off < 16; off <<= 1) {
            int t = __shfl_up(ws, off);
            if (tid >= off) ws += t;
        }
        wsum[tid] = ws;
    }
    __syncthreads();
    const int pref = wv ? wsum[wv - 1] : 0;
    if (i < N_NODES) row_ptr[i] = pref + sc - v;   // tile-local exclusive
    if (tid == 0) blksum[blockIdx.x] = wsum[15];
}

// ---------------------------------------------------------------------------
// Scan stages 2+3 fused: redundant 98-element scan per block, add-back,
// cursor init.
// ---------------------------------------------------------------------------
__global__ __launch_bounds__(256) void k_scan23(
    int* __restrict__ row_ptr, const int* __restrict__ blksum,
    int* __restrict__ cursor)
{
    __shared__ int spref[N_TILES];
    const int tid = threadIdx.x;
    if (tid < 64) {
        int v0 = (tid < N_TILES) ? blksum[tid] : 0;
        int s0 = v0;
        #pragma unroll
        for (int off = 1; off < 64; off <<= 1) {
            int t = __shfl_up(s0, off);
            if (tid >= off) s0 += t;
        }
        if (tid < N_TILES) spref[tid] = s0 - v0;
        int carry = __shfl(s0, 63);
        int i2 = 64 + tid;
        int v1 = (i2 < N_TILES) ? blksum[i2] : 0;
        int s1 = v1;
        #pragma unroll
        for (int off = 1; off < 64; off <<= 1) {
            int t = __shfl_up(s1, off);
            if (tid >= off) s1 += t;
        }
        if (i2 < N_TILES) spref[i2] = carry + s1 - v1;
    }
    __syncthreads();
    const int i = blockIdx.x * 256 + tid;
    if (i < N_NODES) {
        int r = row_ptr[i] + spref[i >> 10];
        row_ptr[i] = r;
        cursor[i] = r;
    }
    if (i == 0) row_ptr[N_NODES] = N_EDGES;
}

// ---------------------------------------------------------------------------
// Slim fill: scatter ONLY dst (4 B) into CSR slot.  Alpha moved into gather
// (R7 measured alpha8 scatter at 300 MB traffic / 134 us).
// ---------------------------------------------------------------------------
__global__ __launch_bounds__(256) void k_fill(
    const int* __restrict__ ei, int* __restrict__ cursor,
    int* __restrict__ dst_sorted)
{
    const int e = blockIdx.x * 256 + threadIdx.x;
    if (e >= N_EDGES) return;
    const int src = ei[e];
    const int dst = ei[N_EDGES + e];
    const int slot = atomicAdd(&cursor[src], 1);
    dst_sorted[slot] = dst;
}

// ---------------------------------------------------------------------------
// Gather + inline alpha + epilogue: one wave per node.
// Per 8-edge chunk, phase 1 (lane = edge*8 + head): each lane computes ONE
// (edge,head) leaky score; softmax over heads = xor-shuffles 1/2/4 shared by
// all 8 edges.  Phase 2 (lane = dim): alpha and dst redistributed by __shfl
// (no LDS).  ~9 wave-instrs/edge amortized vs 15 redundant in R3.
// ---------------------------------------------------------------------------
__global__ __launch_bounds__(256) void k_gather(
    const int* __restrict__ row_ptr, const int* __restrict__ dst_sorted,
    const float* __restrict__ s_src, const float* __restrict__ s_dst,
    const unsigned short* __restrict__ h16, const float* __restrict__ x,
    const float* __restrict__ ln_scale, const float* __restrict__ ln_bias,
    float* __restrict__ out)
{
    const int i = blockIdx.x * 4 + (threadIdx.x >> 6);
    if (i >= N_NODES) return;
    const int lane = threadIdx.x & 63;
    const int g    = lane >> 3;    // phase1: edge-in-chunk; phase2: head
    const int sub  = lane & 7;     // phase1: head

    const int beg = row_ptr[i];
    const int end = row_ptr[i + 1];
    const float ssrc = s_src[i * 8 + sub];
    const float xres = x[(size_t)i * 64 + lane];

    float acc = 0.f;
    for (int chunk = beg; chunk < end; chunk += 8) {
        const int ne = min(8, end - chunk);
        // ---- phase 1: cooperative alpha for 8 edges ----
        const int e = chunk + g;
        int de = 0;
        float sc = 0.f;
        if (e < end) {
            de = dst_sorted[e];                    // 32 B/wave, sequential
            sc = ssrc + s_dst[de * 8 + sub];       // 8x 32 B random, L2-hot
        }
        sc = (sc >= 0.f) ? sc : 0.2f * sc;
        float m = sc;
        m = fmaxf(m, __shfl_xor(m, 1));
        m = fmaxf(m, __shfl_xor(m, 2));
        m = fmaxf(m, __shfl_xor(m, 4));
        const float ex = __expf(sc - m);
        float su = ex;
        su += __shfl_xor(su, 1);
        su += __shfl_xor(su, 2);
        su += __shfl_xor(su, 4);
        const float alpha = ex * __builtin_amdgcn_rcpf(su);

        // ---- phase 2: redistribute via shuffle, 8 independent loads ----
        int   dv[8];
        float av[8];
        #pragma unroll
        for (int j = 0; j < 8; ++j) {
            if (j < ne) {
                dv[j] = __shfl(de, j * 8);
                av[j] = __shfl(alpha, j * 8 + g);
            }
        }
        unsigned short hv[8];
        #pragma unroll
        for (int j = 0; j < 8; ++j)
            if (j < ne) hv[j] = h16[(size_t)dv[j] * 64 + lane];
        #pragma unroll
        for (int j = 0; j < 8; ++j)
            if (j < ne) acc += av[j] * bf2f(hv[j]);
    }

    // epilogue: residual + LayerNorm + L2 normalize
    float v = acc + xres;
    float s = v;
    #pragma unroll
    for (int off = 1; off < 64; off <<= 1) s += __shfl_xor(s, off);
    const float mu = s * (1.f / 64.f);
    const float d = v - mu;
    float vs = d * d;
    #pragma unroll
    for (int off = 1; off < 64; off <<= 1) vs += __shfl_xor(vs, off);
    const float var = vs * (1.f / 64.f);
    float y = d * rsqrtf(var + LN_EPS) * ln_scale[lane] + ln_bias[lane];
    float ss = y * y;
    #pragma unroll
    for (int off = 1; off < 64; off <<= 1) ss += __shfl_xor(ss, off);
    const float norm = sqrtf(ss);
    out[(size_t)i * 64 + lane] = y / fmaxf(norm, NORM_EPS);
}

// ---------------------------------------------------------------------------
extern "C" void kernel_launch(void* const* d_in, const int* in_sizes, int n_in,
                              void* d_out, int out_size, void* d_ws, size_t ws_size,
                              hipStream_t stream)
{
    const float* x        = (const float*)d_in[0];
    const int*   ei       = (const int*)d_in[1];
    const float* W        = (const float*)d_in[2];
    const float* b        = (const float*)d_in[3];
    const float* a        = (const float*)d_in[4];
    const float* ln_scale = (const float*)d_in[5];
    const float* ln_bias  = (const float*)d_in[6];
    float* out = (float*)d_out;

    char* ws = (char*)d_ws;
    size_t off = 0;
    auto alloc = [&](size_t bytes) {
        void* p = ws + off;
        off = (off + bytes + 255) & ~(size_t)255;
        return p;
    };
    unsigned short* h16 = (unsigned short*)alloc((size_t)N_NODES * 64 * 2);
    float* s_src      = (float*)alloc((size_t)N_NODES * 8 * 4);
    float* s_dst      = (float*)alloc((size_t)N_NODES * 8 * 4);
    int*   counts     = (int*)  alloc((size_t)N_NODES * 4);
    int*   row_ptr    = (int*)  alloc((size_t)(N_NODES + 1) * 4);
    int*   cursor     = (int*)  alloc((size_t)N_NODES * 4);
    int*   blksum     = (int*)  alloc((size_t)N_TILES * 4);
    int*   dst_sorted = (int*)  alloc((size_t)N_EDGES * 4);

    hipMemsetAsync(counts, 0, (size_t)N_NODES * 4, stream);

    k_gemm  <<<GEMM_BLOCKS, 256, 0, stream>>>(x, W, b, a, ei, counts,
                                              h16, s_src, s_dst);
    k_scan1 <<<N_TILES, 1024, 0, stream>>>(counts, row_ptr, blksum);
    k_scan23<<<(N_NODES + 255) / 256, 256, 0, stream>>>(row_ptr, blksum, cursor);
    k_fill  <<<(N_EDGES + 255) / 256, 256, 0, stream>>>(ei, cursor, dst_sorted);
    k_gather<<<(N_NODES + 3) / 4,     256, 0, stream>>>(row_ptr, dst_sorted,
                                                        s_src, s_dst, h16, x,
                                                        ln_scale, ln_bias, out);
}